// Round 15
// baseline (7584.829 us; speedup 1.0000x reference)
//
#include <hip/hip_runtime.h>
#include <math.h>

typedef unsigned int u32;
typedef unsigned short u16;
typedef unsigned long long u64;

#define BATCH 64
#define NSUB  4
#define A_TOT 8649
#define TOPN  6000
#define POST  1500
#define NB    4096
#define NT    512
#define NCHUNK 94          // chunk s holds ranks [64s, 64s+64)
#define DONEBIT 0x80000000u
#define CNTMASK 0x7FFFFFFFu
#define CGUARD  (1 << 16)  // consumer loop bound
#define FWAIT   4096       // producer flag-wait bound (then self-service)

// global workspace layout (bytes)
#define WS_RING   0u                   // float4[64][1500]
#define WS_CMASK  1536000u             // u64[64][94]
#define WS_FLAG   1584128u             // u32[64][94]
#define WS_COUNT  1608192u             // u32[64*32] (128B stride per batch)
#define WS_TORCH  1616384u             // u32[64*32]
#define WS_END    1624576u

// LDS layout (bytes); overlapping lifetimes are disjoint:
//  sort:  keys u64[8649] @0; bucketA @69632; bucketB @86016; stemp u32[1024] @102400
//  sub=0: scores u32[6000] @0 (after reg roundtrip); boxes float4[6000] @24064;
//         prank u16[1500] @120064; pend u32 @123064
#define LDS_BYTES 123072

__global__ __launch_bounds__(NT, 1) void roibbox_kernel(
    const float* __restrict__ deltas,    // [B, A, 4]
    const float* __restrict__ probs,     // [B, A]
    const float* __restrict__ anchors,   // [A, 4]
    float* __restrict__ out,             // [B*POST*4] boxes then [B*POST] scores
    char* __restrict__ ws)               // global control workspace
{
    #pragma clang fp contract(off)
    __shared__ alignas(16) char smem[LDS_BYTES];
    u64*    keysL   = (u64*)   (smem + 0);
    u32*    bucketA = (u32*)   (smem + 69632);
    u32*    bucketB = (u32*)   (smem + 86016);
    u32*    stemp   = (u32*)   (smem + 102400);
    u32*    scoresU = (u32*)   (smem + 0);
    float4* boxesL  = (float4*)(smem + 24064);
    u16*    prankL  = (u16*)   (smem + 120064);
    u32*    pendL   = (u32*)   (smem + 123064);

    const int tid = threadIdx.x;
    const u32 b   = (u32)blockIdx.x & 63u;     // batch
    const u32 sub = (u32)blockIdx.x >> 6;      // sub-block (0..3)
    const u32 lane = (u32)tid & 63u;
    const u32 w    = (u32)tid >> 6;
    const float* pb = probs + (size_t)b * A_TOT;

    float4* ringB  = (float4*)(ws + WS_RING)  + (size_t)b * POST;
    u64*    cmaskB = (u64*)   (ws + WS_CMASK) + (size_t)b * NCHUNK;
    u32*    flagB  = (u32*)   (ws + WS_FLAG)  + (size_t)b * NCHUNK;
    u32*    countB = (u32*)   (ws + WS_COUNT) + (size_t)b * 32;
    u32*    torchB = (u32*)   (ws + WS_TORCH) + (size_t)b * 32;

    // ---------- sort (deterministic: buckets fully insertion-sorted) ----------
    #pragma unroll
    for (int i = 0; i < NB/NT; ++i) bucketA[tid + i*NT] = 0u;
    __syncthreads();
    for (int j = tid; j < A_TOT; j += NT) {
        float s = pb[j];
        int bkt = (int)(s * (float)NB);
        bkt = (NB-1) - min(max(bkt, 0), NB-1);
        atomicAdd(&bucketA[bkt], 1u);
    }
    __syncthreads();
    {
        int base8 = tid << 3;
        u32 c[8]; u32 ms = 0;
        #pragma unroll
        for (int i = 0; i < 8; ++i) { c[i] = bucketA[base8+i]; ms += c[i]; }
        stemp[tid] = ms;
        __syncthreads();
        int src = 0;
        for (int off = 1; off < NT; off <<= 1) {
            u32 v = stemp[src*NT + tid];
            if (tid >= off) v += stemp[src*NT + tid - off];
            stemp[(src^1)*NT + tid] = v;
            __syncthreads();
            src ^= 1;
        }
        u32 excl = stemp[src*NT + tid] - ms;
        #pragma unroll
        for (int i = 0; i < 8; ++i) {
            bucketA[base8+i] = excl; bucketB[base8+i] = excl; excl += c[i];
        }
    }
    __syncthreads();
    for (int j = tid; j < A_TOT; j += NT) {
        float s = pb[j];
        int bkt = (int)(s * (float)NB);
        bkt = (NB-1) - min(max(bkt, 0), NB-1);
        u32 pos = atomicAdd(&bucketB[bkt], 1u);
        keysL[pos] = ((u64)__float_as_uint(s) << 32) | (u64)(~(u32)j);
    }
    __syncthreads();
    for (int bkt = tid; bkt < NB; bkt += NT) {
        int begin = (int)bucketA[bkt], end = (int)bucketB[bkt];
        for (int k = begin + 1; k < end; ++k) {
            u64 key = keysL[k];
            int m = k - 1;
            while (m >= begin && keysL[m] < key) { keysL[m+1] = keysL[m]; --m; }
            keysL[m+1] = key;
        }
    }
    __syncthreads();

    auto decodeBox = [&](u64 k) -> float4 {
        u32 aidx = ~((u32)k);
        float4 av = *(const float4*)(anchors + (size_t)aidx * 4);
        float4 dv = *(const float4*)(deltas + ((size_t)b * A_TOT + aidx) * 4);
        float d0 = dv.x*0.1f, d1 = dv.y*0.1f, d2 = dv.z*0.2f, d3 = dv.w*0.2f;
        float ah = av.z - av.x, aw = av.w - av.y;
        float acy = av.x + 0.5f*ah, acx = av.y + 0.5f*aw;
        float h  = (float)exp((double)d2) * ah;   // correctly-rounded fp32 exp
        float wd = (float)exp((double)d3) * aw;
        float cy = d0*ah + acy;                   // contract(off): mul then add
        float cx = d1*aw + acx;
        return make_float4(cy - 0.5f*h, cx - 0.5f*wd, cy + 0.5f*h, cx + 0.5f*wd);
    };

    // ---------- consumer slot keys (before any key overwrite) ----------
    const int nk = (sub < 2) ? 24 : 23;              // chunks owned by this sub
    const int w0 = (sub == 0) ? 1 : 0;               // first consumer wave
    u32 sIdx[4] = {1000u,1000u,1000u,1000u};
    u64 skk[4] = {0ull,0ull,0ull,0ull};
    u32 alm = 0, act = 0;
    if ((int)w >= w0) {
        #pragma unroll
        for (int i = 0; i < 4; ++i) {
            int k = (sub == 0) ? ((int)w - 1) + 7*i : (int)w + 8*i;
            if (k < nk && !(sub != 0 && i >= 3)) {
                u32 s = sub + 4u*(u32)k;
                sIdx[i] = s;
                act |= 1u << i;
                u32 r = s*64u + lane;
                if (r < TOPN) { skk[i] = keysL[r]; alm |= 1u << i; }
            }
        }
    }

    // ---------- sub=0: stage scores+boxes via register roundtrip ----------
    if (sub == 0) {
        u64 kreg[12];
        #pragma unroll
        for (int i = 0; i < 12; ++i) {
            int r = tid + i*NT;
            kreg[i] = (r < TOPN) ? keysL[r] : 0ull;
        }
        __syncthreads();          // keys safe to overwrite
        #pragma unroll
        for (int i = 0; i < 12; ++i) {
            int r = tid + i*NT;
            if (r < TOPN) {
                scoresU[r] = (u32)(kreg[i] >> 32);
                boxesL[r] = decodeBox(kreg[i]);
            }
        }
    }
    // decode consumer slots from saved keys (registers; safe after overwrite)
    float4 cb[4]; float ca[4];
    #pragma unroll
    for (int i = 0; i < 4; ++i) {
        cb[i] = make_float4(0.f,0.f,0.f,0.f); ca[i] = 0.f;
        if ((alm >> i) & 1u) {
            cb[i] = decodeBox(skk[i]);
            ca[i] = (cb[i].z - cb[i].x) * (cb[i].w - cb[i].y);
        }
    }
    __syncthreads();              // boxesL ready for producer

    // suppress iff fl32(inter/den) > 0.7f <=> inter >= MTHR*den (RNE boundary, exact)
    const double MTHR = (double)0.7f + 0x1p-25;

    if (sub == 0 && w == 0) {
        // ================= sole producer (never blocks unboundedly) =================
        u32 pc = 0;
        bool done = false;
        for (u32 s = 0; s < NCHUNK && !done; ++s) {
            bool got = false;
            for (int gg = 0; gg < FWAIT; ++gg) {        // bounded wait for owner FINAL
                u32 fv = __hip_atomic_load(&flagB[s], __ATOMIC_ACQUIRE,
                                           __HIP_MEMORY_SCOPE_AGENT);
                if (fv) { got = true; break; }
                if (gg >= 64) __builtin_amdgcn_s_sleep(1);
            }
            u32 r = s*64u + lane;
            float4 bx = (r < TOPN) ? boxesL[r] : make_float4(0.f,0.f,0.f,0.f);
            float bA = (bx.z - bx.x) * (bx.w - bx.y);
            u64 am;
            if (got) {
                am = cmaskB[s];                         // fresh after acquire
            } else {
                // self-service fallback: derive aliveness from my own picks [0, pc).
                // Exact: suppression is monotone; same f64 predicate as consumers.
                u32 alive = (r < TOPN) ? 1u : 0u;
                if (pc) {
                    u32 q = 0;
                    float4 p0 = ringB[0];
                    float4 p1 = (1u < pc) ? ringB[1] : p0;
                    float4 p2 = (2u < pc) ? ringB[2] : p0;
                    float4 p3 = (3u < pc) ? ringB[3] : p0;
                    for (; q < pc; ++q) {
                        float4 e = p0; p0 = p1; p1 = p2; p2 = p3;
                        if (q+4 < pc) p3 = ringB[q+4];
                        float sA = (e.z - e.x) * (e.w - e.y);
                        float yy1 = fmaxf(e.x, bx.x);
                        float xx1 = fmaxf(e.y, bx.y);
                        float yy2 = fminf(e.z, bx.z);
                        float xx2 = fminf(e.w, bx.w);
                        float inter = fmaxf(yy2 - yy1, 0.f) * fmaxf(xx2 - xx1, 0.f);
                        float den = ((sA + bA) - inter) + 1e-9f;
                        if ((double)inter >= MTHR * (double)den) alive = 0u;
                    }
                }
                am = __ballot(alive);
            }
            if (am) {
                __builtin_amdgcn_s_setprio(1);
                while (am) {
                    u32 ol = (u32)__builtin_ctzll(am);
                    float sy1 = __uint_as_float((u32)__builtin_amdgcn_readlane((int)__float_as_uint(bx.x), (int)ol));
                    float sx1 = __uint_as_float((u32)__builtin_amdgcn_readlane((int)__float_as_uint(bx.y), (int)ol));
                    float sy2 = __uint_as_float((u32)__builtin_amdgcn_readlane((int)__float_as_uint(bx.z), (int)ol));
                    float sx2 = __uint_as_float((u32)__builtin_amdgcn_readlane((int)__float_as_uint(bx.w), (int)ol));
                    if (lane == ol) {
                        prankL[pc] = (u16)r;
                        ringB[pc] = bx;                 // global ring write
                    }
                    float sA = (sy2 - sy1) * (sx2 - sx1);   // bit-exact area recompute
                    float yy1 = fmaxf(sy1, bx.x);
                    float xx1 = fmaxf(sx1, bx.y);
                    float yy2 = fminf(sy2, bx.z);
                    float xx2 = fminf(sx2, bx.w);
                    float inter = fmaxf(yy2 - yy1, 0.f) * fmaxf(xx2 - xx1, 0.f);
                    float den = ((sA + bA) - inter) + 1e-9f;   // exact ref order
                    u64 supp = __ballot((double)inter >= MTHR * (double)den);
                    am &= ~supp;                        // pick suppresses itself too
                    ++pc;
                    if (pc >= POST) {
                        if (lane == 0)
                            __hip_atomic_store(countB, pc | DONEBIT, __ATOMIC_RELEASE,
                                               __HIP_MEMORY_SCOPE_AGENT);
                        done = true; break;
                    }
                    if ((pc & 7u) == 0u && lane == 0)   // publish every 8
                        __hip_atomic_store(countB, pc, __ATOMIC_RELEASE,
                                           __HIP_MEMORY_SCOPE_AGENT);
                }
                __builtin_amdgcn_s_setprio(0);
            }
            if (!done && lane == 0) {
                __hip_atomic_store(countB, pc, __ATOMIC_RELEASE,
                                   __HIP_MEMORY_SCOPE_AGENT);   // final for reign s
                __hip_atomic_store(torchB, s + 1u, __ATOMIC_RELEASE,
                                   __HIP_MEMORY_SCOPE_AGENT);
            }
        }
        if (!done && lane == 0)
            __hip_atomic_store(countB, pc | DONEBIT, __ATOMIC_RELEASE,
                               __HIP_MEMORY_SCOPE_AGENT);
        if (lane == 0) *pendL = pc;
    } else if (act) {
        // ================= consumer (owner) waves — pure accelerator =================
        u32 consumed = 0;

        #define CAPPLY(i, e, sA) do {                                          \
            float yy1 = fmaxf((e).x, cb[i].x);                                 \
            float xx1 = fmaxf((e).y, cb[i].y);                                 \
            float yy2 = fminf((e).z, cb[i].z);                                 \
            float xx2 = fminf((e).w, cb[i].w);                                 \
            float inter = fmaxf(yy2 - yy1, 0.f) * fmaxf(xx2 - xx1, 0.f);       \
            float den = (((sA) + ca[i]) - inter) + 1e-9f;                      \
            if ((double)inter >= MTHR * (double)den) alm &= ~(1u << (i));      \
        } while (0)

        u32 hm = act;
        auto finalize = [&](int i, u64 m) {
            if (lane == 0) {
                cmaskB[sIdx[i]] = m;
                __hip_atomic_store(&flagB[sIdx[i]], 1u, __ATOMIC_RELEASE,
                                   __HIP_MEMORY_SCOPE_AGENT);
            }
            act &= ~(1u << i); hm &= ~(1u << i);
        };
        auto applyBatch = [&](u32 from, u32 to) {
            if (from >= to || !hm) return;
            u32 q = from;
            float4 p0 = ringB[q];
            float4 p1 = (q+1 < to) ? ringB[q+1] : p0;
            float4 p2 = (q+2 < to) ? ringB[q+2] : p0;
            float4 p3 = (q+3 < to) ? ringB[q+3] : p0;
            for (; q < to; ++q) {
                float4 e = p0; p0 = p1; p1 = p2; p2 = p3;
                if (q+4 < to) p3 = ringB[q+4];
                float sA = (e.z - e.x) * (e.w - e.y);
                #pragma unroll
                for (int i = 0; i < 4; ++i)
                    if ((hm >> i) & 1u) CAPPLY(i, e, sA);
            }
            #pragma unroll
            for (int i = 0; i < 4; ++i)
                if (((hm >> i) & 1u) && !__ballot((alm >> i) & 1u))
                    finalize(i, 0ull);              // early-finalize dead chunk
        };

        int bk = 0;
        for (int g = 0; g < CGUARD && act; ++g) {
            u32 t  = __hip_atomic_load(torchB, __ATOMIC_ACQUIRE, __HIP_MEMORY_SCOPE_AGENT);
            u32 pv = __hip_atomic_load(countB, __ATOMIC_ACQUIRE, __HIP_MEMORY_SCOPE_AGENT);
            u32 cnt = pv & CNTMASK;
            bool did = false;
            if (cnt > consumed) { applyBatch(consumed, cnt); consumed = cnt; did = true; }
            // torch-driven finalize: count loaded after torch acquire is final
            #pragma unroll
            for (int i = 0; i < 4; ++i) {
                if (((act >> i) & 1u) && sIdx[i] <= t) {
                    finalize(i, __ballot((alm >> i) & 1u));
                    did = true;
                }
            }
            if (pv & DONEBIT) break;
            if (!did) {
                if      (bk == 0) __builtin_amdgcn_s_sleep(1);
                else if (bk == 1) __builtin_amdgcn_s_sleep(2);
                else if (bk == 2) __builtin_amdgcn_s_sleep(4);
                else              __builtin_amdgcn_s_sleep(8);
                if (bk < 3) ++bk;
            } else bk = 0;
        }
        #undef CAPPLY
    }
    __syncthreads();

    // ---------- epilogue (sub=0 only) ----------
    if (sub == 0) {
        u32 pend = *pendL;
        const size_t sbase = (size_t)BATCH * POST * 4;
        for (u32 p = (u32)tid; p < pend; p += NT) {
            float4 e = ringB[p];
            u32 rr = (u32)prankL[p];
            size_t row = (size_t)b * POST + p;
            float* ob = out + row * 4;
            ob[0] = fminf(fmaxf(e.x, 0.f), 1.f);
            ob[1] = fminf(fmaxf(e.y, 0.f), 1.f);
            ob[2] = fminf(fmaxf(e.z, 0.f), 1.f);
            ob[3] = fminf(fmaxf(e.w, 0.f), 1.f);
            out[sbase + row] = __uint_as_float(scoresU[rr]);
        }
        for (u32 p = pend + (u32)tid; p < POST; p += NT) {
            size_t row = (size_t)b * POST + p;
            float* ob = out + row * 4;
            ob[0]=0.f; ob[1]=0.f; ob[2]=0.f; ob[3]=0.f;
            out[sbase + row] = 0.f;
        }
    }
}

extern "C" void kernel_launch(void* const* d_in, const int* in_sizes, int n_in,
                              void* d_out, int out_size, void* d_ws, size_t ws_size,
                              hipStream_t stream) {
    const float* deltas  = (const float*)d_in[0];  // [64,31,31,36] f32
    const float* probs   = (const float*)d_in[1];  // [64,31,31,9]  f32
    // d_in[2] = gt_labels (unused)
    const float* anchors = (const float*)d_in[3];  // [8649,4] f32
    float* out = (float*)d_out;                    // 480000 f32
    char* ws = (char*)d_ws;

    // zero control region (cmask/flags/count/torch) — stream-ordered, capturable
    (void)hipMemsetAsync(ws + WS_CMASK, 0, WS_END - WS_CMASK, stream);
    roibbox_kernel<<<dim3(BATCH * NSUB), dim3(NT), 0, stream>>>(
        deltas, probs, anchors, out, ws);
}